// Round 2
// baseline (229.225 us; speedup 1.0000x reference)
//
#include <hip/hip_runtime.h>

#define BATCH 4096
#define DICT  16384
#define KDIM  512
#define CAT   128
#define BT    128
#define DCH   128

typedef __attribute__((ext_vector_type(4)))  float f32x4;
typedef __attribute__((ext_vector_type(16))) float f32x16;
typedef __attribute__((ext_vector_type(8)))  short short8;
typedef __attribute__((ext_vector_type(8)))  unsigned short ushort8;
typedef __attribute__((ext_vector_type(2)))  unsigned int uintx2;

__device__ __forceinline__ unsigned short f2bf(float f) {
  unsigned int u = __float_as_uint(f);
  return (unsigned short)((u + 0x7fffu + ((u >> 16) & 1u)) >> 16);  // RNE
}

#define AS1 __attribute__((address_space(1)))
#define AS3 __attribute__((address_space(3)))
__device__ __forceinline__ void gl_lds16(const void* g, void* l) {
  // dest = wave-uniform LDS base (+lane*16 by HW); source is per-lane (pre-swizzled)
  __builtin_amdgcn_global_load_lds((AS1 void*)(g), (AS3 void*)(l), 16, 0, 0);
}

#define MFMA32(a, b, c) __builtin_amdgcn_mfma_f32_32x32x16_bf16((a), (b), (c), 0, 0, 0)

// ---------- prep: rows -> bf16 + sum of squares (x and keys) ----------
__global__ void prep_rows(const float* __restrict__ in,
                          unsigned short* __restrict__ ob,
                          float* __restrict__ sums) {
  const int lane = threadIdx.x & 63, wv = threadIdx.x >> 6;
  const int row = blockIdx.x * 4 + wv;
  const float* rp = in + ((size_t)row << 9);
  float4 a = *(const float4*)(rp + lane * 8);
  float4 b = *(const float4*)(rp + lane * 8 + 4);
  float s = a.x*a.x + a.y*a.y + a.z*a.z + a.w*a.w
          + b.x*b.x + b.y*b.y + b.z*b.z + b.w*b.w;
  ushort8 o;
  o[0]=f2bf(a.x); o[1]=f2bf(a.y); o[2]=f2bf(a.z); o[3]=f2bf(a.w);
  o[4]=f2bf(b.x); o[5]=f2bf(b.y); o[6]=f2bf(b.z); o[7]=f2bf(b.w);
  *(ushort8*)(ob + ((size_t)row << 9) + lane * 8) = o;
  #pragma unroll
  for (int m = 32; m; m >>= 1) s += __shfl_xor(s, m);
  if (lane == 0) sums[row] = s;
}

// ---------- prep: V (16384x128) -> Vt bf16 (128x16384) ----------
__global__ void prep_vt(const float* __restrict__ V,
                        unsigned short* __restrict__ Vt) {
  __shared__ float t[64][129];
  const int d0 = blockIdx.x * 64;
  const int tid = threadIdx.x;
  #pragma unroll
  for (int j = 0; j < 32; ++j) {
    int idx = j * 256 + tid;
    t[idx >> 7][idx & 127] = V[((size_t)d0 << 7) + idx];
  }
  __syncthreads();
  #pragma unroll
  for (int j = 0; j < 32; ++j) {
    int idx = j * 256 + tid;
    int cc = idx >> 6, dd = idx & 63;
    Vt[((size_t)cc << 14) + d0 + dd] = f2bf(t[dd][cc]);
  }
}

// ---------- fused: S = keys.x^T (32x32 MFMA); kern=1e4/(sq+1); KV_part += kern^T V ----------
// LDS (52KB): As[64 d-pair rows][256B] | Bs[64 b-pair rows][256B] | Vs[64 c-pair rows][256B]
//             | sks (4KB).  Ps[128 b][256B d] overlays As+Bs after GEMM1.
// All tiles pair-packed to 256B rows, XOR-swizzled by (row&15)<<4 -> 2-way max (free).
__global__ __launch_bounds__(256, 3)
void varkeys_fused(const unsigned short* __restrict__ xb,
                   const unsigned short* __restrict__ kb,
                   const unsigned short* __restrict__ vt,
                   const float* __restrict__ sx,
                   const float* __restrict__ sk,
                   float* __restrict__ kvp,
                   int dsl, int ndc) {
  __shared__ __attribute__((aligned(16))) char lds[53248];
  char* const As = lds;                 // 16KB
  char* const Bs = lds + 16384;         // 16KB
  char* const Vs = lds + 32768;         // 16KB (one 64-d half of Vt chunk)
  char* const Ps = lds;                 // 32KB overlay on As+Bs
  float* const sks = (float*)(lds + 49152);

  const int tid = threadIdx.x;
  const int lane = tid & 63, h = lane >> 5, r31 = lane & 31;
  const int wv = tid >> 6;
  const int dw = wv >> 1, bw = wv & 1;     // GEMM1 wave roles (d-half, b-half)
  const int bw2 = wv >> 1, cw2 = wv & 1;   // GEMM2 wave roles (b-half, c-half)

  const int bid = blockIdx.x;
  const int btile = bid & 31, dslice = bid >> 5;
  const int b0 = btile * BT;
  const int dbase = dslice * dsl;

  if (tid * 4 < dsl) {
    f32x4 v = *(const f32x4*)(sk + dbase + tid * 4);
    *(f32x4*)(sks + tid * 4) = v;
  }
  const float sxv0 = sx[b0 + bw * 64 + r31];
  const float sxv1 = sx[b0 + bw * 64 + 32 + r31];

  // ---- staging per-thread constants (linear LDS dest <-> swizzled global src) ----
  const int sex   = (tid & 15) ^ (tid >> 4);        // (unit ^ row&15)
  const int srow  = 2 * (tid >> 4) + (sex >> 3);    // src row within 32-row group
  const int skoff = (sex & 7) << 4;                 // k-unit byte offset
  const size_t ksrc_t = (size_t)srow * 1024 + skoff;   // keys/x rows: 1024B
  const size_t vsrc_t = (size_t)srow * 32768 + skoff;  // vt rows: 32768B

  // ---- frag-read per-lane constants ----
  const int MH  = (((r31 & 1) << 3) | h) ^ (r31 >> 1);   // pair-pack row XOR key
  int T[4];
  #pragma unroll
  for (int ks = 0; ks < 4; ++ks) T[ks] = ((ks << 1) ^ MH) << 4;
  const int PSW = (r31 & 15) << 4;        // P-row swizzle (rows 256B)
  const int PH  = (h << 4) ^ PSW;         // P-read dk-term base
  const int PW  = (h << 3) ^ PSW;         // P-write term base
  const int arb = (dw * 32 + (r31 >> 1)) * 256;    // A row base
  const int brb = (bw * 32 + (r31 >> 1)) * 256;    // B row base
  const int vrb = (cw2 * 32 + (r31 >> 1)) * 256;   // V row base
  const int prb = (bw2 * 64 + r31) * 256;          // P read row base
  const int pwb = (bw * 64 + r31) * 256;           // P write row base

  const char* xbB = (const char*)xb;
  const char* kbB = (const char*)kb;
  const char* vtB = (const char*)vt;

  const f32x16 z16 = {0.f};
  f32x16 acc[2][2];
  acc[0][0] = z16; acc[0][1] = z16; acc[1][0] = z16; acc[1][1] = z16;

  for (int dc = 0; dc < ndc; ++dc) {
    const int dg0 = dbase + dc * DCH;
    f32x16 S00 = z16, S01 = z16, S10 = z16, S11 = z16;

    for (int kk = 0; kk < KDIM / 64; ++kk) {
      __syncthreads();   // prior readers of As/Bs (and Ps at kk=0) done
      const size_t ksrc = (size_t)dg0 * 1024 + (size_t)(kk * 128) + ksrc_t;
      const size_t xsrc = (size_t)b0 * 1024 + (size_t)(kk * 128) + ksrc_t;
      #pragma unroll
      for (int p = 0; p < 4; ++p) {
        gl_lds16(kbB + ksrc + (size_t)p * 32768, As + p * 4096 + wv * 1024);
        gl_lds16(xbB + xsrc + (size_t)p * 32768, Bs + p * 4096 + wv * 1024);
      }
      if (kk >= 6) {     // stage Vs half0 under the last two k-chunks
        const size_t vsrc = vsrc_t + (size_t)dg0 * 2;
        #pragma unroll
        for (int pp = 0; pp < 2; ++pp) {
          int p = (kk - 6) * 2 + pp;
          gl_lds16(vtB + vsrc + (size_t)p * 1048576, Vs + p * 4096 + wv * 1024);
        }
      }
      __syncthreads();   // staging visible (vmcnt drained by barrier)
      #pragma unroll
      for (int ks = 0; ks < 4; ++ks) {
        short8 a0 = *(const short8*)(As + arb + T[ks]);
        short8 a1 = *(const short8*)(As + arb + 4096 + T[ks]);
        short8 bf0 = *(const short8*)(Bs + brb + T[ks]);
        short8 bf1 = *(const short8*)(Bs + brb + 4096 + T[ks]);
        S00 = MFMA32(a0, bf0, S00);
        S01 = MFMA32(a0, bf1, S01);
        S10 = MFMA32(a1, bf0, S10);
        S11 = MFMA32(a1, bf1, S11);
      }
    }

    __syncthreads();   // all GEMM1 frag reads done -> safe to overlay Ps on As/Bs

    // transform: kern = 1e4/(sk + sx - 2 dot + 1) -> bf16 -> Ps[b][d] (swizzled)
    const float* sksb = sks + dc * DCH + dw * 64 + h * 4;
    #pragma unroll
    for (int i = 0; i < 2; ++i) {
      #pragma unroll
      for (int j = 0; j < 2; ++j) {
        const float sxv = j ? sxv1 : sxv0;
        const f32x16 s = (i == 0) ? (j == 0 ? S00 : S01) : (j == 0 ? S10 : S11);
        char* pw = Ps + pwb + j * 8192;   // (bw*64 + j*32 + r31) * 256
        #pragma unroll
        for (int q = 0; q < 4; ++q) {
          f32x4 skv = *(const f32x4*)(sksb + i * 32 + q * 8);
          float k0 = 10000.f * __builtin_amdgcn_rcpf(skv[0] + sxv - 2.f * s[q*4+0] + 1.f);
          float k1 = 10000.f * __builtin_amdgcn_rcpf(skv[1] + sxv - 2.f * s[q*4+1] + 1.f);
          float k2 = 10000.f * __builtin_amdgcn_rcpf(skv[2] + sxv - 2.f * s[q*4+2] + 1.f);
          float k3 = 10000.f * __builtin_amdgcn_rcpf(skv[3] + sxv - 2.f * s[q*4+3] + 1.f);
          uintx2 w;
          w[0] = (unsigned int)f2bf(k0) | ((unsigned int)f2bf(k1) << 16);
          w[1] = (unsigned int)f2bf(k2) | ((unsigned int)f2bf(k3) << 16);
          *(uintx2*)(pw + ((dw * 128 + i * 64 + q * 16) ^ PW)) = w;
        }
      }
    }
    __syncthreads();   // P visible to all waves; Vs half0 ready

    // GEMM2: acc[b][c] += P[b][d] * Vt^T[d][c], d in two 64-halves
    #pragma unroll
    for (int half = 0; half < 2; ++half) {
      if (half) {
        __syncthreads();   // half0 V reads done
        const size_t vsrc = vsrc_t + (size_t)(dg0 + 64) * 2;
        #pragma unroll
        for (int p = 0; p < 4; ++p)
          gl_lds16(vtB + vsrc + (size_t)p * 1048576, Vs + p * 4096 + wv * 1024);
        __syncthreads();   // half1 staged
      }
      #pragma unroll
      for (int dk2 = 0; dk2 < 4; ++dk2) {
        const int du = ((half * 4 + dk2) << 5) ^ PH;
        short8 pa0 = *(const short8*)(Ps + prb + du);
        short8 pa1 = *(const short8*)(Ps + prb + 8192 + du);
        short8 v0 = *(const short8*)(Vs + vrb + T[dk2]);
        short8 v1 = *(const short8*)(Vs + vrb + 4096 + T[dk2]);
        acc[0][0] = MFMA32(pa0, v0, acc[0][0]);
        acc[0][1] = MFMA32(pa0, v1, acc[0][1]);
        acc[1][0] = MFMA32(pa1, v0, acc[1][0]);
        acc[1][1] = MFMA32(pa1, v1, acc[1][1]);
      }
    }
  }

  // epilogue: write this slice's partial KV (wave owns distinct b-half x c-half)
  float* outb = kvp + ((size_t)(dslice * BATCH + b0 + bw2 * 64) << 7) + cw2 * 64;
  #pragma unroll
  for (int jm = 0; jm < 2; ++jm)
    #pragma unroll
    for (int q = 0; q < 4; ++q)
      #pragma unroll
      for (int rr = 0; rr < 4; ++rr) {
        int brow = jm * 32 + q * 8 + h * 4 + rr;
        float* o = outb + ((size_t)brow << 7);
        o[r31]      = acc[jm][0][q * 4 + rr];
        o[32 + r31] = acc[jm][1][q * 4 + rr];
      }
}

// ---------- reduce nd slices + row-normalize ----------
__global__ void reduce_norm(const float* __restrict__ part, float* __restrict__ out,
                            int nd) {
  const int lane = threadIdx.x & 63, wv = threadIdx.x >> 6;
  const int b = blockIdx.x * 4 + wv;
  float v0 = 0.f, v1 = 0.f;
  for (int s = 0; s < nd; ++s) {
    const float* p = part + ((((size_t)s << 12) + b) << 7);
    v0 += p[lane]; v1 += p[lane + 64];
  }
  float t = v0 + v1;
  #pragma unroll
  for (int m = 32; m; m >>= 1) t += __shfl_xor(t, m);
  out[((size_t)b << 7) + lane]      = v0 / t;
  out[((size_t)b << 7) + lane + 64] = v1 / t;
}

extern "C" void kernel_launch(void* const* d_in, const int* in_sizes, int n_in,
                              void* d_out, int out_size, void* d_ws, size_t ws_size,
                              hipStream_t stream) {
  (void)in_sizes; (void)n_in; (void)out_size;
  const float* x    = (const float*)d_in[0];
  const float* keys = (const float*)d_in[1];
  const float* V    = (const float*)d_in[2];
  float* out = (float*)d_out;
  char* ws = (char*)d_ws;
  // ws: xb 4M | kb 16M @4M | vt 4M @20M | sx @24M | sk @24M+64K | kvp @25M (nd*2MB)
  unsigned short* xb = (unsigned short*)(ws);
  unsigned short* kb = (unsigned short*)(ws + ((size_t)4 << 20));
  unsigned short* vt = (unsigned short*)(ws + ((size_t)20 << 20));
  float* sx  = (float*)(ws + ((size_t)24 << 20));
  float* sk  = (float*)(ws + ((size_t)24 << 20) + (1 << 16));
  float* kvp = (float*)(ws + ((size_t)25 << 20));

  const int nd  = (ws_size >= ((size_t)90 << 20)) ? 32 : 16;  // split-K granularity
  const int dsl = DICT / nd;
  const int ndc = dsl / DCH;

  prep_rows<<<BATCH / 4, 256, 0, stream>>>(x, xb, sx);
  prep_rows<<<DICT / 4, 256, 0, stream>>>(keys, kb, sk);
  prep_vt<<<DICT / 64, 256, 0, stream>>>(V, vt);
  varkeys_fused<<<32 * nd, 256, 0, stream>>>(xb, kb, vt, sx, sk, kvp, dsl, ndc);
  reduce_norm<<<BATCH / 4, 256, 0, stream>>>(kvp, out, nd);
}

// Round 3
// 167.429 us; speedup vs baseline: 1.3691x; 1.3691x over previous
//
#include <hip/hip_runtime.h>

#define BATCH 4096
#define DICT  16384
#define KDIM  512
#define CAT   128
#define ND    16              // split-K over dict (FIXED - nd=32 tripled FETCH in R2)
#define DSLICE (DICT/ND)      // 1024
#define DCH   64              // d-chunk per dc iteration
#define BT    128             // b rows per block

typedef __attribute__((ext_vector_type(4))) float          f32x4;
typedef __attribute__((ext_vector_type(8))) short          short8;
typedef __attribute__((ext_vector_type(8))) unsigned short ushort8;

__device__ __forceinline__ unsigned short f2bf(float f) {
  unsigned int u = __float_as_uint(f);
  return (unsigned short)((u + 0x7fffu + ((u >> 16) & 1u)) >> 16);  // RNE
}

#define AS1 __attribute__((address_space(1)))
#define AS3 __attribute__((address_space(3)))
__device__ __forceinline__ void gl_lds16(const void* g, void* l) {
  // 16B/lane; LDS dest = wave-uniform base + lane*16 (linear). Swizzle is
  // pre-applied on the GLOBAL source address (m173 pattern).
  __builtin_amdgcn_global_load_lds((AS1 void*)(g), (AS3 void*)(l), 16, 0, 0);
}

#define MFMA16(a, b, c) __builtin_amdgcn_mfma_f32_16x16x32_bf16((a), (b), (c), 0, 0, 0)

// ---------- prep: rows -> bf16 + sum of squares (x and keys) ----------
__global__ void prep_rows(const float* __restrict__ in,
                          unsigned short* __restrict__ ob,
                          float* __restrict__ sums) {
  const int lane = threadIdx.x & 63, wv = threadIdx.x >> 6;
  const int row = blockIdx.x * 4 + wv;
  const float* rp = in + ((size_t)row << 9);
  float4 a = *(const float4*)(rp + lane * 8);
  float4 b = *(const float4*)(rp + lane * 8 + 4);
  float s = a.x*a.x + a.y*a.y + a.z*a.z + a.w*a.w
          + b.x*b.x + b.y*b.y + b.z*b.z + b.w*b.w;
  ushort8 o;
  o[0]=f2bf(a.x); o[1]=f2bf(a.y); o[2]=f2bf(a.z); o[3]=f2bf(a.w);
  o[4]=f2bf(b.x); o[5]=f2bf(b.y); o[6]=f2bf(b.z); o[7]=f2bf(b.w);
  *(ushort8*)(ob + ((size_t)row << 9) + lane * 8) = o;
  #pragma unroll
  for (int m = 32; m; m >>= 1) s += __shfl_xor(s, m);
  if (lane == 0) sums[row] = s;
}

// ---------- prep: V (16384x128) -> Vt bf16 (128x16384) ----------
__global__ void prep_vt(const float* __restrict__ V,
                        unsigned short* __restrict__ Vt) {
  __shared__ float t[64][129];
  const int d0 = blockIdx.x * 64;
  const int tid = threadIdx.x;
  #pragma unroll
  for (int j = 0; j < 32; ++j) {
    int idx = j * 256 + tid;
    t[idx >> 7][idx & 127] = V[((size_t)d0 << 7) + idx];
  }
  __syncthreads();
  #pragma unroll
  for (int j = 0; j < 32; ++j) {
    int idx = j * 256 + tid;
    int cc = idx >> 6, dd = idx & 63;
    Vt[((size_t)cc << 14) + d0 + dd] = f2bf(t[dd][cc]);
  }
}

// ---------- fused kernel (R1 fragment math; 2-phase dbuf, 1 barrier/k-step) ----------
// LDS (68KB): As[2][64 d][128B] | Bs[2][128 b][128B] | Ps[4 wv][32 b][128B] | sks 4KB
// GEMM2 B-frags (Vt) read DIRECT from global (L2-resident) - no Vs, no V barriers.
__global__ __launch_bounds__(256, 2)
void varkeys_fused(const unsigned short* __restrict__ xb,
                   const unsigned short* __restrict__ kb,
                   const unsigned short* __restrict__ vt,
                   const float* __restrict__ sx,
                   const float* __restrict__ sk,
                   float* __restrict__ kvp) {
  __shared__ __attribute__((aligned(16))) char lds[69632];
  char* const Ps = lds + 49152;              // 16KB, per-wave 4KB, no barrier
  float* const sks = (float*)(lds + 65536);  // 4KB

  const int tid  = threadIdx.x;
  const int lane = tid & 63;
  const int wv   = tid >> 6;
  const int c    = lane & 15;
  const int h    = lane >> 4;
  const int sw   = (lane & 7) << 4;

  const int bid    = blockIdx.x;
  const int btile  = bid & 31;
  const int dslice = bid >> 5;
  const int b0     = btile * BT;
  const int dbase  = dslice * DSLICE;

  { f32x4 v = *(const f32x4*)(sk + dbase + tid * 4);
    *(f32x4*)(sks + tid * 4) = v; }
  const float sxv0 = sx[b0 + wv * 32 + c];
  const float sxv1 = sx[b0 + wv * 32 + 16 + c];

  // staging per-thread constants (linear LDS dest <-> swizzled global src)
  int rwA[2], ofA[2], rwB[4], ofB[4];
  #pragma unroll
  for (int r = 0; r < 4; ++r) {
    int L = r * 4096 + wv * 1024 + lane * 16;
    int row = L >> 7, inb = L & 127;
    if (r < 2) { rwA[r] = row; ofA[r] = inb ^ ((row & 7) << 4); }
    rwB[r] = row; ofB[r] = inb ^ ((row & 7) << 4);
  }

  const char* xbB = (const char*)xb;
  const char* kbB = (const char*)kb;
  const char* vtB = (const char*)vt;

  const f32x4 zero = {0.f, 0.f, 0.f, 0.f};
  f32x4 acc[2][8];
  #pragma unroll
  for (int i = 0; i < 2; ++i)
    #pragma unroll
    for (int j = 0; j < 8; ++j) acc[i][j] = zero;

  // ---- stage one 64-k step of keys(64 rows) + x(128 rows) into buffer `buf` ----
  auto stage = [&](int dg2, int kbyte, int buf) {
    char* A2 = lds + buf * 8192;
    char* B2 = lds + 16384 + buf * 16384;
    #pragma unroll
    for (int r = 0; r < 2; ++r)
      gl_lds16(kbB + (((size_t)(dg2 + rwA[r])) << 10) + kbyte + ofA[r],
               A2 + r * 4096 + wv * 1024);
    #pragma unroll
    for (int r = 0; r < 4; ++r)
      gl_lds16(xbB + (((size_t)(b0 + rwB[r])) << 10) + kbyte + ofB[r],
               B2 + r * 4096 + wv * 1024);
  };

  int cur = 0;
  stage(dbase, 0, 0);   // prologue: (dc=0, kk=0) -> buf0

  for (int dc = 0; dc < DSLICE / DCH; ++dc) {
    const int dg = dbase + dc * DCH;

    f32x4 S[4][2];
    #pragma unroll
    for (int i = 0; i < 4; ++i) { S[i][0] = zero; S[i][1] = zero; }

    #pragma unroll
    for (int kk = 0; kk < KDIM / 64; ++kk) {
      __syncthreads();   // drains stage(cur); separates prior reads of buf cur^1
      const int ns = dc * 8 + kk + 1;
      if (ns < 128)
        stage(dbase + (ns >> 3) * DCH, (ns & 7) << 7, cur ^ 1);

      const char* As = lds + cur * 8192;
      const char* Bs = lds + 16384 + cur * 16384;
      #pragma unroll
      for (int kf = 0; kf < 2; ++kf) {
        const int ko = (kf * 64 + h * 16) ^ sw;
        short8 bf0 = *(const short8*)(Bs + ((wv * 32 + c) << 7) + ko);
        short8 bf1 = *(const short8*)(Bs + ((wv * 32 + 16 + c) << 7) + ko);
        #pragma unroll
        for (int i = 0; i < 4; ++i) {
          short8 af = *(const short8*)(As + ((i * 16 + c) << 7) + ko);
          S[i][0] = MFMA16(af, bf0, S[i][0]);
          S[i][1] = MFMA16(af, bf1, S[i][1]);
        }
      }
      cur ^= 1;
    }

    // transform: kern = 1e4/(sk + sx - 2 dot + 1) -> bf16 -> per-wave Ps (no barrier)
    #pragma unroll
    for (int i = 0; i < 4; ++i) {
      const f32x4 skv = *(const f32x4*)(sks + dc * 64 + i * 16 + h * 4);
      #pragma unroll
      for (int fj = 0; fj < 2; ++fj) {
        const float sxv = fj ? sxv1 : sxv0;
        f32x4 s = S[i][fj];
        float k0 = 10000.f * __builtin_amdgcn_rcpf(skv[0] + sxv - 2.f * s[0] + 1.f);
        float k1 = 10000.f * __builtin_amdgcn_rcpf(skv[1] + sxv - 2.f * s[1] + 1.f);
        float k2 = 10000.f * __builtin_amdgcn_rcpf(skv[2] + sxv - 2.f * s[2] + 1.f);
        float k3 = 10000.f * __builtin_amdgcn_rcpf(skv[3] + sxv - 2.f * s[3] + 1.f);
        unsigned int w0 = (unsigned int)f2bf(k0) | ((unsigned int)f2bf(k1) << 16);
        unsigned int w1 = (unsigned int)f2bf(k2) | ((unsigned int)f2bf(k3) << 16);
        int b = fj * 16 + c;
        char* p = Ps + (wv << 12) + (b << 7) + ((i * 32 + h * 8) ^ sw);
        ((unsigned int*)p)[0] = w0;
        ((unsigned int*)p)[1] = w1;
      }
    }

    // GEMM2: acc[b][c] += P[b][d] * Vt^T[d][c]; P same-wave LDS, V direct global
    #pragma unroll
    for (int dk = 0; dk < 2; ++dk) {
      const int ko = (dk * 64 + h * 16) ^ sw;
      short8 pa0 = *(const short8*)(Ps + (wv << 12) + (c << 7) + ko);
      short8 pa1 = *(const short8*)(Ps + (wv << 12) + ((16 + c) << 7) + ko);
      const char* vbase = vtB + ((size_t)c << 15)
                        + ((size_t)(dg + dk * 32 + h * 8) << 1);
      #pragma unroll
      for (int fc = 0; fc < 8; ++fc) {
        short8 vb = *(const short8*)(vbase + ((size_t)fc << 19)); // fc*16 rows *32KB
        acc[0][fc] = MFMA16(pa0, vb, acc[0][fc]);
        acc[1][fc] = MFMA16(pa1, vb, acc[1][fc]);
      }
    }
  }

  // epilogue: write this slice's partial KV
  float* op = kvp + (((size_t)dslice * BATCH + b0 + wv * 32) << 7);
  #pragma unroll
  for (int fb = 0; fb < 2; ++fb)
    #pragma unroll
    for (int r = 0; r < 4; ++r) {
      int brow = fb * 16 + h * 4 + r;
      #pragma unroll
      for (int fc = 0; fc < 8; ++fc)
        op[((size_t)brow << 7) + fc * 16 + c] = acc[fb][fc][r];
    }
}

// ---------- reduce ND slices + row-normalize ----------
__global__ void reduce_norm(const float* __restrict__ part, float* __restrict__ out) {
  const int lane = threadIdx.x & 63, wv = threadIdx.x >> 6;
  const int b = blockIdx.x * 4 + wv;
  float v0 = 0.f, v1 = 0.f;
  #pragma unroll
  for (int s = 0; s < ND; ++s) {
    const float* p = part + ((((size_t)s << 12) + b) << 7);
    v0 += p[lane]; v1 += p[lane + 64];
  }
  float t = v0 + v1;
  #pragma unroll
  for (int m = 32; m; m >>= 1) t += __shfl_xor(t, m);
  out[((size_t)b << 7) + lane]      = v0 / t;
  out[((size_t)b << 7) + lane + 64] = v1 / t;
}

extern "C" void kernel_launch(void* const* d_in, const int* in_sizes, int n_in,
                              void* d_out, int out_size, void* d_ws, size_t ws_size,
                              hipStream_t stream) {
  (void)in_sizes; (void)n_in; (void)out_size; (void)ws_size;
  const float* x    = (const float*)d_in[0];
  const float* keys = (const float*)d_in[1];
  const float* V    = (const float*)d_in[2];
  float* out = (float*)d_out;
  char* ws = (char*)d_ws;
  // ws (57MB): xb 4M | kb 16M @4M | vt 4M @20M | sx @24M | sk @24M+64K | kvp 32M @25M
  unsigned short* xb = (unsigned short*)(ws);
  unsigned short* kb = (unsigned short*)(ws + ((size_t)4 << 20));
  unsigned short* vt = (unsigned short*)(ws + ((size_t)20 << 20));
  float* sx  = (float*)(ws + ((size_t)24 << 20));
  float* sk  = (float*)(ws + ((size_t)24 << 20) + (1 << 16));
  float* kvp = (float*)(ws + ((size_t)25 << 20));

  prep_rows<<<BATCH / 4, 256, 0, stream>>>(x, xb, sx);
  prep_rows<<<DICT / 4, 256, 0, stream>>>(keys, kb, sk);
  prep_vt<<<DICT / 64, 256, 0, stream>>>(V, vt);
  varkeys_fused<<<32 * ND, 256, 0, stream>>>(xb, kb, vt, sx, sk, kvp);
  reduce_norm<<<BATCH / 4, 256, 0, stream>>>(kvp, out);
}

// Round 4
// 161.584 us; speedup vs baseline: 1.4186x; 1.0362x over previous
//
#include <hip/hip_runtime.h>

#define BATCH 4096
#define DICT  16384
#define KDIM  512
#define CAT   128
#define ND    16
#define DSLICE (DICT/ND)      // 1024
#define DCH   128             // d-chunk per dc iteration
#define BT    128             // b rows per block

typedef __attribute__((ext_vector_type(4)))  float f32x4;
typedef __attribute__((ext_vector_type(16))) float f32x16;
typedef __attribute__((ext_vector_type(8)))  short short8;
typedef __attribute__((ext_vector_type(8)))  unsigned short ushort8;
typedef __attribute__((ext_vector_type(4)))  int intx4;

__device__ __forceinline__ unsigned short f2bf(float f) {
  unsigned int u = __float_as_uint(f);
  return (unsigned short)((u + 0x7fffu + ((u >> 16) & 1u)) >> 16);  // RNE
}

__device__ __forceinline__ unsigned int cvtpk_bf16(float lo, float hi) {
  unsigned int r;
  asm volatile("v_cvt_pk_bf16_f32 %0, %1, %2" : "=v"(r) : "v"(lo), "v"(hi));
  return r;
}

// a' = {a[0:31], b[0:31]}  (lane>=32 reads b's low half)
// b' = {a[32:63], b[32:63]}
__device__ __forceinline__ void pl32swap(unsigned int& a, unsigned int& b) {
  asm volatile("v_permlane32_swap_b32 %0, %1" : "+v"(a), "+v"(b));
}

#define AS1 __attribute__((address_space(1)))
#define AS3 __attribute__((address_space(3)))
__device__ __forceinline__ void gl_lds16(const void* g, void* l) {
  // dest = wave-uniform LDS base (+lane*16 by HW); source per-lane (pre-swizzled)
  __builtin_amdgcn_global_load_lds((AS1 void*)(g), (AS3 void*)(l), 16, 0, 0);
}

#define MFMA32(a, b, c) __builtin_amdgcn_mfma_f32_32x32x16_bf16((a), (b), (c), 0, 0, 0)

// ---------- prep: rows -> bf16 + sum of squares (x and keys) ----------
__global__ void prep_rows(const float* __restrict__ in,
                          unsigned short* __restrict__ ob,
                          float* __restrict__ sums) {
  const int lane = threadIdx.x & 63, wv = threadIdx.x >> 6;
  const int row = blockIdx.x * 4 + wv;
  const float* rp = in + ((size_t)row << 9);
  float4 a = *(const float4*)(rp + lane * 8);
  float4 b = *(const float4*)(rp + lane * 8 + 4);
  float s = a.x*a.x + a.y*a.y + a.z*a.z + a.w*a.w
          + b.x*b.x + b.y*b.y + b.z*b.z + b.w*b.w;
  ushort8 o;
  o[0]=f2bf(a.x); o[1]=f2bf(a.y); o[2]=f2bf(a.z); o[3]=f2bf(a.w);
  o[4]=f2bf(b.x); o[5]=f2bf(b.y); o[6]=f2bf(b.z); o[7]=f2bf(b.w);
  *(ushort8*)(ob + ((size_t)row << 9) + lane * 8) = o;
  #pragma unroll
  for (int m = 32; m; m >>= 1) s += __shfl_xor(s, m);
  if (lane == 0) sums[row] = s;
}

// ---------- prep: V (16384x128) -> Vt bf16 (128x16384) ----------
__global__ void prep_vt(const float* __restrict__ V,
                        unsigned short* __restrict__ Vt) {
  __shared__ float t[64][129];
  const int d0 = blockIdx.x * 64;
  const int tid = threadIdx.x;
  #pragma unroll
  for (int j = 0; j < 32; ++j) {
    int idx = j * 256 + tid;
    t[idx >> 7][idx & 127] = V[((size_t)d0 << 7) + idx];
  }
  __syncthreads();
  #pragma unroll
  for (int j = 0; j < 32; ++j) {
    int idx = j * 256 + tid;
    int cc = idx >> 6, dd = idx & 63;
    Vt[((size_t)cc << 14) + d0 + dd] = f2bf(t[dd][cc]);
  }
}

// ---------- fused: S=keys.x^T (32x32, 2x2); kern->bf16 IN-REGISTER; KV += P^T V ----------
// LDS (68KB): As 16K (128d x 64k) | Bs 16K (128b x 64k) | Vs 32K (2 x 128c x 64d) | sks 4K
// All tiles pair-packed into 256B rows, XOR-swizzled (R2-verified layout, 2-way max).
// GEMM2 A-frags built from S registers via cvt_pk_bf16 + permlane32_swap (no P in LDS).
// Waves: (dw=wv>>1) x (bw=wv&1); wave GEMM1 tile 64d x 64b; per-wave partial KV over
// its d-half reduced across dw-pairs in the epilogue through LDS.
__global__ __launch_bounds__(256, 2)
void varkeys_fused(const unsigned short* __restrict__ xb,
                   const unsigned short* __restrict__ kb,
                   const unsigned short* __restrict__ vt,
                   const float* __restrict__ sx,
                   const float* __restrict__ sk,
                   float* __restrict__ kvp) {
  __shared__ __attribute__((aligned(16))) char lds[69632];
  char* const As = lds;                      // 16KB
  char* const Bs = lds + 16384;              // 16KB
  char* const Vs = lds + 32768;              // 32KB
  float* const sks = (float*)(lds + 65536);  // 4KB

  const int tid = threadIdx.x;
  const int lane = tid & 63, r31 = lane & 31, h = lane >> 5;
  const int wv = tid >> 6;
  const int dw = wv >> 1, bw = wv & 1;

  const int bid = blockIdx.x;
  const int btile = bid & 31, dslice = bid >> 5;
  const int b0 = btile * BT;
  const int dbase = dslice * DSLICE;

  { f32x4 v = *(const f32x4*)(sk + dbase + tid * 4);
    *(f32x4*)(sks + tid * 4) = v; }
  const float sxv0 = sx[b0 + bw * 64 + r31];
  const float sxv1 = sx[b0 + bw * 64 + 32 + r31];

  // staging constants (R2-verified): linear LDS dest <-> swizzled global source
  const int sex   = (tid & 15) ^ (tid >> 4);
  const int srow  = 2 * (tid >> 4) + (sex >> 3);
  const int skoff = (sex & 7) << 4;
  const size_t ksrc_t = (size_t)srow * 1024 + skoff;   // kb/xb row stride 1024B
  const size_t vsrc_t = (size_t)srow * 32768 + skoff;  // vt row stride 32768B

  // frag-read constants (R2-verified)
  const int MH = (((r31 & 1) << 3) | h) ^ (r31 >> 1);
  int T[4];
  #pragma unroll
  for (int ks = 0; ks < 4; ++ks) T[ks] = ((ks << 1) ^ MH) << 4;
  const int arb = (dw * 32 + (r31 >> 1)) * 256;
  const int brb = (bw * 32 + (r31 >> 1)) * 256;
  const int vrb = (r31 >> 1) * 256;

  const char* xbB = (const char*)xb;
  const char* kbB = (const char*)kb;
  const char* vtB = (const char*)vt;

  const f32x16 z16 = {0.f};
  f32x16 acc[2][4];
  #pragma unroll
  for (int j = 0; j < 2; ++j)
    #pragma unroll
    for (int n = 0; n < 4; ++n) acc[j][n] = z16;

  for (int dc = 0; dc < DSLICE / DCH; ++dc) {
    const int dg0 = dbase + dc * DCH;
    f32x16 S00 = z16, S01 = z16, S10 = z16, S11 = z16;

    for (int kk = 0; kk < KDIM / 64; ++kk) {
      __syncthreads();   // readers of As/Bs (and Vs of prior dc) done
      const size_t ksrc = (size_t)dg0 * 1024 + (size_t)(kk * 128) + ksrc_t;
      const size_t xsrc = (size_t)b0 * 1024 + (size_t)(kk * 128) + ksrc_t;
      #pragma unroll
      for (int p = 0; p < 4; ++p) {
        gl_lds16(kbB + ksrc + (size_t)p * 32768, As + p * 4096 + wv * 1024);
        gl_lds16(xbB + xsrc + (size_t)p * 32768, Bs + p * 4096 + wv * 1024);
      }
      if (kk >= 4) {     // stage Vs (32KB) in 8 rounds under kk=4..7
        #pragma unroll
        for (int t = 0; t < 2; ++t) {
          const int rr = (kk - 4) * 2 + t;      // 0..7
          const int hv = rr >> 2, cg = rr & 3;  // d-half, c-group
          const size_t vsrc = (size_t)(cg * 32) * 32768
                            + (size_t)(dg0 + hv * 64) * 2 + vsrc_t;
          gl_lds16(vtB + vsrc, Vs + rr * 4096 + wv * 1024);
        }
      }
      __syncthreads();   // staged data visible
      #pragma unroll
      for (int ks = 0; ks < 4; ++ks) {
        short8 a0  = *(const short8*)(As + arb + T[ks]);
        short8 a1  = *(const short8*)(As + arb + 4096 + T[ks]);
        short8 bf0 = *(const short8*)(Bs + brb + T[ks]);
        short8 bf1 = *(const short8*)(Bs + brb + 4096 + T[ks]);
        S00 = MFMA32(a0, bf0, S00);
        S01 = MFMA32(a0, bf1, S01);
        S10 = MFMA32(a1, bf0, S10);
        S11 = MFMA32(a1, bf1, S11);
      }
    }

    // transform + in-register P-frag build + GEMM2, per 16-d chunk tl of this
    // wave's 64-d half.  S reg md = (r&3)+8*(r>>2)+4h; A-frag needs d=8h+i per
    // 16-chunk -> cvt_pk pairs + permlane32_swap assemble it exactly.
    const float* sksb = sks + dc * DCH + dw * 64 + h * 4;
    #pragma unroll
    for (int tl = 0; tl < 4; ++tl) {
      const int i = tl >> 1, c2 = tl & 1;
      short8 pa[2];
      #pragma unroll
      for (int j = 0; j < 2; ++j) {
        const f32x16 Sv = (i == 0) ? (j == 0 ? S00 : S01) : (j == 0 ? S10 : S11);
        const float sxv = j ? sxv1 : sxv0;
        float kq[8];
        #pragma unroll
        for (int q2 = 0; q2 < 2; ++q2) {
          const int q = c2 * 2 + q2;
          const f32x4 skv = *(const f32x4*)(sksb + i * 32 + q * 8);
          #pragma unroll
          for (int rr = 0; rr < 4; ++rr)
            kq[q2 * 4 + rr] =
              10000.f * __builtin_amdgcn_rcpf(skv[rr] + sxv - 2.f * Sv[q * 4 + rr] + 1.f);
        }
        unsigned int X = cvtpk_bf16(kq[0], kq[1]);   // md {0,1}+16c2 (+4h)
        unsigned int Z = cvtpk_bf16(kq[2], kq[3]);   // md {2,3}
        unsigned int Y = cvtpk_bf16(kq[4], kq[5]);   // md {8,9}
        unsigned int W = cvtpk_bf16(kq[6], kq[7]);   // md {10,11}
        pl32swap(X, Y);   // X -> frag word0, Y -> word2
        pl32swap(Z, W);   // Z -> word1, W -> word3
        intx4 fw; fw[0] = (int)X; fw[1] = (int)Z; fw[2] = (int)Y; fw[3] = (int)W;
        pa[j] = *(short8*)&fw;
      }
      #pragma unroll
      for (int n = 0; n < 4; ++n) {
        short8 vb = *(const short8*)(Vs + dw * 16384 + n * 4096 + vrb + T[tl]);
        acc[0][n] = MFMA32(pa[0], vb, acc[0][n]);
        acc[1][n] = MFMA32(pa[1], vb, acc[1][n]);
      }
    }
  }

  // ---- epilogue: reduce KV partials across dw-pairs via LDS, store ----
  __syncthreads();   // all GEMM2 LDS reads done; safe to reuse As/Bs/Vs
  if (dw == 1) {
    #pragma unroll
    for (int j = 0; j < 2; ++j)
      #pragma unroll
      for (int n = 0; n < 4; ++n)
        #pragma unroll
        for (int s = 0; s < 4; ++s) {
          f32x4 t;
          t[0] = acc[j][n][s*4+0]; t[1] = acc[j][n][s*4+1];
          t[2] = acc[j][n][s*4+2]; t[3] = acc[j][n][s*4+3];
          *(f32x4*)(lds + bw * 32768 + ((j * 4 + n) * 4 + s) * 1024 + lane * 16) = t;
        }
  }
  __syncthreads();
  if (dw == 0) {
    #pragma unroll
    for (int j = 0; j < 2; ++j)
      #pragma unroll
      for (int n = 0; n < 4; ++n)
        #pragma unroll
        for (int s = 0; s < 4; ++s) {
          f32x4 t = *(const f32x4*)(lds + bw * 32768 + ((j * 4 + n) * 4 + s) * 1024 + lane * 16);
          acc[j][n][s*4+0] += t[0]; acc[j][n][s*4+1] += t[1];
          acc[j][n][s*4+2] += t[2]; acc[j][n][s*4+3] += t[3];
        }
    float* op = kvp + (((size_t)(dslice * BATCH + b0 + bw * 64)) << 7);
    #pragma unroll
    for (int j = 0; j < 2; ++j)
      #pragma unroll
      for (int n = 0; n < 4; ++n)
        #pragma unroll
        for (int r = 0; r < 16; ++r) {
          int row = j * 32 + (r & 3) + 8 * (r >> 2) + 4 * h;
          op[((size_t)row << 7) + n * 32 + r31] = acc[j][n][r];
        }
  }
}

// ---------- reduce ND slices + row-normalize ----------
__global__ void reduce_norm(const float* __restrict__ part, float* __restrict__ out) {
  const int lane = threadIdx.x & 63, wv = threadIdx.x >> 6;
  const int b = blockIdx.x * 4 + wv;
  float v0 = 0.f, v1 = 0.f;
  #pragma unroll
  for (int s = 0; s < ND; ++s) {
    const float* p = part + ((((size_t)s << 12) + b) << 7);
    v0 += p[lane]; v1 += p[lane + 64];
  }
  float t = v0 + v1;
  #pragma unroll
  for (int m = 32; m; m >>= 1) t += __shfl_xor(t, m);
  out[((size_t)b << 7) + lane]      = v0 / t;
  out[((size_t)b << 7) + lane + 64] = v1 / t;
}

extern "C" void kernel_launch(void* const* d_in, const int* in_sizes, int n_in,
                              void* d_out, int out_size, void* d_ws, size_t ws_size,
                              hipStream_t stream) {
  (void)in_sizes; (void)n_in; (void)out_size; (void)ws_size;
  const float* x    = (const float*)d_in[0];
  const float* keys = (const float*)d_in[1];
  const float* V    = (const float*)d_in[2];
  float* out = (float*)d_out;
  char* ws = (char*)d_ws;
  // ws (57MB): xb 4M | kb 16M @4M | vt 4M @20M | sx @24M | sk @24M+64K | kvp 32M @25M
  unsigned short* xb = (unsigned short*)(ws);
  unsigned short* kb = (unsigned short*)(ws + ((size_t)4 << 20));
  unsigned short* vt = (unsigned short*)(ws + ((size_t)20 << 20));
  float* sx  = (float*)(ws + ((size_t)24 << 20));
  float* sk  = (float*)(ws + ((size_t)24 << 20) + (1 << 16));
  float* kvp = (float*)(ws + ((size_t)25 << 20));

  prep_rows<<<BATCH / 4, 256, 0, stream>>>(x, xb, sx);
  prep_rows<<<DICT / 4, 256, 0, stream>>>(keys, kb, sk);
  prep_vt<<<DICT / 64, 256, 0, stream>>>(V, vt);
  varkeys_fused<<<32 * ND, 256, 0, stream>>>(xb, kb, vt, sx, sk, kvp);
  reduce_norm<<<BATCH / 4, 256, 0, stream>>>(kvp, out);
}

// Round 5
// 139.298 us; speedup vs baseline: 1.6456x; 1.1600x over previous
//
#include <hip/hip_runtime.h>

#define BATCH 4096
#define DICT  16384
#define KDIM  512
#define CAT   128
#define ND    16              // split-K over dict
#define DSLICE (DICT/ND)      // 1024
#define DCH   64              // d-chunk per dc iteration
#define BT    256             // b rows per block (8 waves x 32)

typedef __attribute__((ext_vector_type(4))) float          f32x4;
typedef __attribute__((ext_vector_type(8))) short          short8;
typedef __attribute__((ext_vector_type(8))) unsigned short ushort8;

__device__ __forceinline__ unsigned short f2bf(float f) {
  unsigned int u = __float_as_uint(f);
  return (unsigned short)((u + 0x7fffu + ((u >> 16) & 1u)) >> 16);  // RNE
}

#define AS1 __attribute__((address_space(1)))
#define AS3 __attribute__((address_space(3)))
__device__ __forceinline__ void gl_lds16(const void* g, void* l) {
  // 16B/lane; LDS dest = wave-uniform base + lane*16 (linear). Swizzle is
  // pre-applied on the GLOBAL source address (m173 pattern).
  __builtin_amdgcn_global_load_lds((AS1 void*)(g), (AS3 void*)(l), 16, 0, 0);
}

template <int N>
__device__ __forceinline__ void waitv() {
  if constexpr (N == 0)      asm volatile("s_waitcnt vmcnt(0)" ::: "memory");
  else if constexpr (N == 5) asm volatile("s_waitcnt vmcnt(5)" ::: "memory");
  else                       asm volatile("s_waitcnt vmcnt(6)" ::: "memory");
  __builtin_amdgcn_sched_barrier(0);   // rule #18: pin ops after the waitcnt
}

#define MFMA16(a, b, c) __builtin_amdgcn_mfma_f32_16x16x32_bf16((a), (b), (c), 0, 0, 0)

// ---------- prep: rows -> bf16 + sum of squares (x and keys) ----------
__global__ void prep_rows(const float* __restrict__ in,
                          unsigned short* __restrict__ ob,
                          float* __restrict__ sums) {
  const int lane = threadIdx.x & 63, wv = threadIdx.x >> 6;
  const int row = blockIdx.x * 4 + wv;
  const float* rp = in + ((size_t)row << 9);
  float4 a = *(const float4*)(rp + lane * 8);
  float4 b = *(const float4*)(rp + lane * 8 + 4);
  float s = a.x*a.x + a.y*a.y + a.z*a.z + a.w*a.w
          + b.x*b.x + b.y*b.y + b.z*b.z + b.w*b.w;
  ushort8 o;
  o[0]=f2bf(a.x); o[1]=f2bf(a.y); o[2]=f2bf(a.z); o[3]=f2bf(a.w);
  o[4]=f2bf(b.x); o[5]=f2bf(b.y); o[6]=f2bf(b.z); o[7]=f2bf(b.w);
  *(ushort8*)(ob + ((size_t)row << 9) + lane * 8) = o;
  #pragma unroll
  for (int m = 32; m; m >>= 1) s += __shfl_xor(s, m);
  if (lane == 0) sums[row] = s;
}

// ---------- prep: V (16384x128) -> Vt bf16 (128x16384) ----------
__global__ void prep_vt(const float* __restrict__ V,
                        unsigned short* __restrict__ Vt) {
  __shared__ float t[64][129];
  const int d0 = blockIdx.x * 64;
  const int tid = threadIdx.x;
  #pragma unroll
  for (int j = 0; j < 32; ++j) {
    int idx = j * 256 + tid;
    t[idx >> 7][idx & 127] = V[((size_t)d0 << 7) + idx];
  }
  __syncthreads();
  #pragma unroll
  for (int j = 0; j < 32; ++j) {
    int idx = j * 256 + tid;
    int cc = idx >> 6, dd = idx & 63;
    Vt[((size_t)cc << 14) + d0 + dd] = f2bf(t[dd][cc]);
  }
}

// ---------- fused kernel: R1 fragment math, counted-vmcnt double-buffer pipeline ----------
// 512 threads (8 waves), BT=256, 1 block/CU.  LDS 128KB:
//   As dbuf 2x8KB | Bs dbuf 2x32KB | Vs 16KB | Ps 8x4KB (per-wave, no barrier)
// Per k-step: s_barrier ; stage(next -> buf^1) ; s_waitcnt vmcnt(C) ; s_barrier ; MFMA(buf).
// vmcnt never drains to 0 in the main loop (T4).  V staged at slots kn=4,5; sk in regs.
__global__ __launch_bounds__(512, 2)
void varkeys_fused(const unsigned short* __restrict__ xb,
                   const unsigned short* __restrict__ kb,
                   const unsigned short* __restrict__ vt,
                   const float* __restrict__ sx,
                   const float* __restrict__ sk,
                   float* __restrict__ kvp) {
  __shared__ __attribute__((aligned(16))) char lds[131072];
  char* const VsB = lds + 81920;             // 16KB
  char* const PsB = lds + 98304;             // 32KB (wv*4096 each)

  const int tid  = threadIdx.x;
  const int lane = tid & 63;
  const int wv   = tid >> 6;                 // 0..7
  const int c    = lane & 15;
  const int h    = lane >> 4;
  const int sw   = (lane & 7) << 4;
  const int l3   = lane >> 3;

  const int bid    = blockIdx.x;
  const int btile  = bid & 15;
  const int dslice = bid >> 4;
  const int b0     = btile * BT;
  const int dbase  = dslice * DSLICE;

  const float sxv0 = sx[b0 + wv * 32 + c];
  const float sxv1 = sx[b0 + wv * 32 + 16 + c];

  // staging per-thread constants (linear LDS dest <-> swizzled global src)
  const int rowA  = wv * 8 + l3;                       // As row 0..63
  const int rowB0 = wv * 32 + l3;                      // Bs row base (+ r*8)
  const int ofs   = (((lane & 7) ^ l3) << 4);          // swizzled in-row offset

  const char* xbB = (const char*)xb;
  const char* kbB = (const char*)kb;
  const char* vtB = (const char*)vt;
  char* const Ps  = PsB + (wv << 12);

  const f32x4 zero = {0.f, 0.f, 0.f, 0.f};
  f32x4 acc[2][8];
  #pragma unroll
  for (int i = 0; i < 2; ++i)
    #pragma unroll
    for (int j = 0; j < 8; ++j) acc[i][j] = zero;

  // prologue: stage (dc=0, kk=0) -> buf0   (5 loads/wave)
  gl_lds16(kbB + ((size_t)(dbase + rowA) << 10) + ofs, lds + wv * 1024);
  #pragma unroll
  for (int r = 0; r < 4; ++r)
    gl_lds16(xbB + ((size_t)(b0 + rowB0 + r * 8) << 10) + ofs,
             lds + 16384 + (wv * 4 + r) * 1024);

  f32x4 skq[4];

  for (int dc = 0; dc < DSLICE / DCH; ++dc) {
    const int dg = dbase + dc * DCH;

    f32x4 S[4][2];
    #pragma unroll
    for (int i = 0; i < 4; ++i) { S[i][0] = zero; S[i][1] = zero; }

    #pragma unroll
    for (int kk = 0; kk < 8; ++kk) {
      __builtin_amdgcn_s_barrier();          // A: all waves done reading buf[kk&1^1]
      if (kk == 0) {                         // sk for THIS dc's transform (7 slots early)
        #pragma unroll
        for (int i = 0; i < 4; ++i)
          skq[i] = *(const f32x4*)(sk + dg + i * 16 + h * 4);
      }
      // stage(ns+1) -> buf[(kk+1)&1]
      if (!(kk == 7 && dc == (DSLICE / DCH - 1))) {
        const int dg2 = (kk == 7) ? dg + DCH : dg;
        const int kb2 = ((kk + 1) & 7) << 7;
        char* A2 = lds + ((kk + 1) & 1) * 8192;
        char* B2 = lds + 16384 + ((kk + 1) & 1) * 32768;
        gl_lds16(kbB + ((size_t)(dg2 + rowA) << 10) + kb2 + ofs, A2 + wv * 1024);
        #pragma unroll
        for (int r = 0; r < 4; ++r)
          gl_lds16(xbB + ((size_t)(b0 + rowB0 + r * 8) << 10) + kb2 + ofs,
                   B2 + (wv * 4 + r) * 1024);
        if (kk == 3)   // V rows 0..63 of this dc (ready long before GEMM2)
          gl_lds16(vtB + ((size_t)(wv * 8 + l3) << 15) + ((size_t)dg << 1) + ofs,
                   VsB + wv * 1024);
        if (kk == 4)   // V rows 64..127
          gl_lds16(vtB + ((size_t)(64 + wv * 8 + l3) << 15) + ((size_t)dg << 1) + ofs,
                   VsB + 8192 + wv * 1024);
      }
      // wait: exactly this step's issues remain in flight -> prev step's landed
      if (kk == 7) { if (dc == DSLICE / DCH - 1) waitv<0>(); else waitv<5>(); }
      else if (kk == 3 || kk == 4) waitv<6>();
      else waitv<5>();
      __builtin_amdgcn_s_barrier();          // B: everyone's stage(ns) landed
      __builtin_amdgcn_sched_barrier(0);

      // GEMM1 k-step on buf[kk&1]  (R1-verified fragment math)
      const char* As = lds + (kk & 1) * 8192;
      const char* Bs = lds + 16384 + (kk & 1) * 32768;
      #pragma unroll
      for (int kf = 0; kf < 2; ++kf) {
        const int ko = (kf * 64 + h * 16) ^ sw;
        short8 bf0 = *(const short8*)(Bs + ((wv * 32 + c) << 7) + ko);
        short8 bf1 = *(const short8*)(Bs + ((wv * 32 + 16 + c) << 7) + ko);
        #pragma unroll
        for (int i = 0; i < 4; ++i) {
          short8 af = *(const short8*)(As + ((i * 16 + c) << 7) + ko);
          S[i][0] = MFMA16(af, bf0, S[i][0]);
          S[i][1] = MFMA16(af, bf1, S[i][1]);
        }
      }
    }

    // transform: kern = 1e4/(sk + sx - 2 dot + 1) -> bf16 -> per-wave Ps (no barrier)
    #pragma unroll
    for (int i = 0; i < 4; ++i) {
      const f32x4 skv = skq[i];
      #pragma unroll
      for (int fj = 0; fj < 2; ++fj) {
        const float sxv = fj ? sxv1 : sxv0;
        f32x4 s = S[i][fj];
        float k0 = 10000.f * __builtin_amdgcn_rcpf(skv[0] + sxv - 2.f * s[0] + 1.f);
        float k1 = 10000.f * __builtin_amdgcn_rcpf(skv[1] + sxv - 2.f * s[1] + 1.f);
        float k2 = 10000.f * __builtin_amdgcn_rcpf(skv[2] + sxv - 2.f * s[2] + 1.f);
        float k3 = 10000.f * __builtin_amdgcn_rcpf(skv[3] + sxv - 2.f * s[3] + 1.f);
        unsigned int w0 = (unsigned int)f2bf(k0) | ((unsigned int)f2bf(k1) << 16);
        unsigned int w1 = (unsigned int)f2bf(k2) | ((unsigned int)f2bf(k3) << 16);
        int b = fj * 16 + c;
        char* p = Ps + (b << 7) + ((i * 32 + h * 8) ^ sw);
        ((unsigned int*)p)[0] = w0;
        ((unsigned int*)p)[1] = w1;
      }
    }

    // GEMM2: acc[b][c] += P[b][d] * Vt^T[d][c]; P same-wave LDS, V staged in Vs
    #pragma unroll
    for (int dk = 0; dk < 2; ++dk) {
      const int ko = (dk * 64 + h * 16) ^ sw;
      short8 pa0 = *(const short8*)(Ps + (c << 7) + ko);
      short8 pa1 = *(const short8*)(Ps + ((16 + c) << 7) + ko);
      #pragma unroll
      for (int fc = 0; fc < 8; ++fc) {
        short8 vb = *(const short8*)(VsB + ((fc * 16 + c) << 7) + ko);
        acc[0][fc] = MFMA16(pa0, vb, acc[0][fc]);
        acc[1][fc] = MFMA16(pa1, vb, acc[1][fc]);
      }
    }
  }

  // epilogue: write this slice's partial KV
  float* op = kvp + (((size_t)dslice * BATCH + b0 + wv * 32) << 7);
  #pragma unroll
  for (int fb = 0; fb < 2; ++fb)
    #pragma unroll
    for (int r = 0; r < 4; ++r) {
      int brow = fb * 16 + h * 4 + r;
      #pragma unroll
      for (int fc = 0; fc < 8; ++fc)
        op[((size_t)brow << 7) + fc * 16 + c] = acc[fb][fc][r];
    }
}

// ---------- reduce ND slices + row-normalize ----------
__global__ void reduce_norm(const float* __restrict__ part, float* __restrict__ out) {
  const int lane = threadIdx.x & 63, wv = threadIdx.x >> 6;
  const int b = blockIdx.x * 4 + wv;
  float v0 = 0.f, v1 = 0.f;
  #pragma unroll
  for (int s = 0; s < ND; ++s) {
    const float* p = part + ((((size_t)s << 12) + b) << 7);
    v0 += p[lane]; v1 += p[lane + 64];
  }
  float t = v0 + v1;
  #pragma unroll
  for (int m = 32; m; m >>= 1) t += __shfl_xor(t, m);
  out[((size_t)b << 7) + lane]      = v0 / t;
  out[((size_t)b << 7) + lane + 64] = v1 / t;
}

extern "C" void kernel_launch(void* const* d_in, const int* in_sizes, int n_in,
                              void* d_out, int out_size, void* d_ws, size_t ws_size,
                              hipStream_t stream) {
  (void)in_sizes; (void)n_in; (void)out_size; (void)ws_size;
  const float* x    = (const float*)d_in[0];
  const float* keys = (const float*)d_in[1];
  const float* V    = (const float*)d_in[2];
  float* out = (float*)d_out;
  char* ws = (char*)d_ws;
  // ws (57MB): xb 4M | kb 16M @4M | vt 4M @20M | sx @24M | sk @24M+64K | kvp 32M @25M
  unsigned short* xb = (unsigned short*)(ws);
  unsigned short* kb = (unsigned short*)(ws + ((size_t)4 << 20));
  unsigned short* vt = (unsigned short*)(ws + ((size_t)20 << 20));
  float* sx  = (float*)(ws + ((size_t)24 << 20));
  float* sk  = (float*)(ws + ((size_t)24 << 20) + (1 << 16));
  float* kvp = (float*)(ws + ((size_t)25 << 20));

  prep_rows<<<BATCH / 4, 256, 0, stream>>>(x, xb, sx);
  prep_rows<<<DICT / 4, 256, 0, stream>>>(keys, kb, sk);
  prep_vt<<<DICT / 64, 256, 0, stream>>>(V, vt);
  varkeys_fused<<<(BATCH / BT) * ND, 512, 0, stream>>>(xb, kb, vt, sx, sk, kvp);
  reduce_norm<<<BATCH / 4, 256, 0, stream>>>(kvp, out);
}